// Round 19
// baseline (33.643 us; speedup 1.0000x reference)
//
#include <hip/hip_runtime.h>

// GSplat renderer: global bf16 tables + pure-GEMM MFMA kernel.
// R18 lesson: in-kernel staging recomputed exp2 tables 16x redundantly
// (16.8M vs 1M distinct) -> staging dominated gs_mfma (~85% of inst volume).
// Now: params once -> tables once (A_t = col_c*ey 4MB, B_t = ex 1MB, bf16,
// natural layout) -> GEMM stages via reg-staging (global dwordx4 + XOR-
// swizzled ds_write_b128) -> MFMA loop identical to R18 -> finalize.

constexpr int PIX = 65536;
constexpr int KSPLIT = 8;
constexpr int MT = 64;
constexpr int NT = 64;
constexpr int KCH = 128;     // k per staging chunk (256B rows in LDS)
constexpr float COORD_STEP = 2.0f / 255.0f;

typedef __attribute__((ext_vector_type(8))) short short8;
typedef __attribute__((ext_vector_type(4))) float f32x4;

__device__ __forceinline__ unsigned cvt_pk_bf16(float lo, float hi) {
  unsigned r;
  asm("v_cvt_pk_bf16_f32 %0, %1, %2" : "=v"(r) : "v"(lo), "v"(hi));
  return r;
}

// ---------- kernel 1: per-gaussian params (once) ----------
__global__ __launch_bounds__(256) void gs_params(
    const float* __restrict__ means, const float* __restrict__ scales,
    const float* __restrict__ opac, const float* __restrict__ colors,
    float4* __restrict__ params, float4* __restrict__ colp) {
  int n = blockIdx.x * 256 + threadIdx.x;
  float mx = means[3 * n], my = means[3 * n + 1], mz = means[3 * n + 2];
  float scl = fmaxf((scales[3 * n] + scales[3 * n + 1] + scales[3 * n + 2]) * (1.0f / 3.0f), 1e-4f);
  float op = opac[n];
  float rzs = 1.0f / (fabsf(mz) + 1.0f);
  float sigma = fminf(fmaxf(scl * rzs, 0.02f), 0.5f);
  float inv_s = 1.0f / sigma;
  float K = -0.72134752044f * inv_s * inv_s;  // -0.5/ln2 * inv_s^2
  params[n] = make_float4(tanhf(mx * rzs), tanhf(my * rzs), K, op);
  colp[n] = make_float4(op * colors[3 * n], op * colors[3 * n + 1],
                        op * colors[3 * n + 2], op);
}

// ---------- kernel 2: tables (1M exp2 total, natural layout) ----------
// bid<256: A rows (A_t[c][row][k] = col_c[k]*exp2(K dy^2), bf16)
// bid>=256: B cols (B_t[col][k] = exp2(K dx^2), bf16)
__global__ __launch_bounds__(256) void gs_tables(
    const float4* __restrict__ params, const float4* __restrict__ colp,
    unsigned short* __restrict__ A_t, unsigned short* __restrict__ B_t) {
  int t = threadIdx.x;
  int bid = blockIdx.x;
  int k0 = t * 8;
  if (bid < 256) {
    int row = bid;
    float cr = -1.0f + COORD_STEP * (float)row;
    float ev[8];
    float4 cp[8];
#pragma unroll
    for (int j = 0; j < 8; ++j) {
      float4 p = params[k0 + j];
      float dy = cr - p.y;
      ev[j] = exp2f(p.z * dy * dy);
      cp[j] = colp[k0 + j];
    }
    size_t base = (size_t)row * 2048 + k0;  // elements
#pragma unroll
    for (int c = 0; c < 4; ++c) {
      float v[8];
#pragma unroll
      for (int j = 0; j < 8; ++j) {
        float cc = (c == 0) ? cp[j].x : (c == 1) ? cp[j].y : (c == 2) ? cp[j].z : cp[j].w;
        v[j] = ev[j] * cc;
      }
      uint4 pk = make_uint4(cvt_pk_bf16(v[0], v[1]), cvt_pk_bf16(v[2], v[3]),
                            cvt_pk_bf16(v[4], v[5]), cvt_pk_bf16(v[6], v[7]));
      *(uint4*)(A_t + (size_t)c * 524288 + base) = pk;
    }
  } else {
    int col = bid - 256;
    float ccd = -1.0f + COORD_STEP * (float)col;
    float v[8];
#pragma unroll
    for (int j = 0; j < 8; ++j) {
      float4 p = params[k0 + j];
      float dx = ccd - p.x;
      v[j] = exp2f(p.z * dx * dx);
    }
    uint4 pk = make_uint4(cvt_pk_bf16(v[0], v[1]), cvt_pk_bf16(v[2], v[3]),
                          cvt_pk_bf16(v[4], v[5]), cvt_pk_bf16(v[6], v[7]));
    *(uint4*)(B_t + (size_t)col * 2048 + k0) = pk;
  }
}

// ---------- kernel 3: GEMM (M=1024, N=256, K=2048, KSPLIT=8) ----------
__global__ __launch_bounds__(256) void gs_gemm(
    const unsigned short* __restrict__ A_t, const unsigned short* __restrict__ B_t,
    float* __restrict__ partials) {
  __shared__ unsigned short A_l[MT * KCH];  // 16 KB, swizzled
  __shared__ unsigned short B_l[NT * KCH];  // 16 KB, swizzled

  const int t = threadIdx.x;
  const int mt = blockIdx.x;          // 0..15: c = mt>>2, rowband (mt&3)*64
  const int nt = blockIdx.y;          // 0..3
  const int kp = blockIdx.z;          // 0..7
  const int c = mt >> 2;
  const int row0 = (mt & 3) * MT;
  const int col0 = nt * NT;

  const int w = t >> 6;
  const int lane = t & 63;
  const int lr = t & 15;
  const int lg = (t >> 4) & 3;

  const int ra = w * 16 + lr;
  const unsigned offA = (unsigned)(ra * 256 + lg * 16);
  const unsigned swA = (unsigned)((ra & 7) << 4);
  const unsigned swB = (unsigned)((lr & 7) << 4);
  const unsigned offB0 = (unsigned)((0 * 16 + lr) * 256 + lg * 16);
  const unsigned offB1 = (unsigned)((1 * 16 + lr) * 256 + lg * 16);
  const unsigned offB2 = (unsigned)((2 * 16 + lr) * 256 + lg * 16);
  const unsigned offB3 = (unsigned)((3 * 16 + lr) * 256 + lg * 16);

  f32x4 acc0 = {0.f, 0.f, 0.f, 0.f};
  f32x4 acc1 = acc0, acc2 = acc0, acc3 = acc0;

  // staging lane mapping: inst covers 4 rows (64 lanes x 16B = 1024B)
  const int mrow_sub = lane >> 4;       // 0..3
  const int kb = (lane & 15) * 16;      // byte within 256B row-slice

  for (int cc = 0; cc < 2; ++cc) {
    const size_t ksl = (size_t)kp * 512 + cc * 256;  // byte offset in k
    // --- reg-stage: 4 A-loads + 4 B-loads per wave, then swizzled ds_writes
    uint4 va[4], vb[4];
#pragma unroll
    for (int i = 0; i < 4; ++i) {
      int inst = w * 4 + i;           // 0..15
      int m = inst * 4 + mrow_sub;    // 0..63
      va[i] = *(const uint4*)((const char*)A_t + (size_t)c * 1048576 +
                              (size_t)(row0 + m) * 4096 + ksl + kb);
      vb[i] = *(const uint4*)((const char*)B_t +
                              (size_t)(col0 + m) * 4096 + ksl + kb);
    }
    if (cc) __syncthreads();          // prior MFMA reads done before overwrite
#pragma unroll
    for (int i = 0; i < 4; ++i) {
      int inst = w * 4 + i;
      int m = inst * 4 + mrow_sub;
      unsigned ds = (unsigned)((m * 256 + kb) ^ ((m & 7) << 4));
      *(uint4*)((char*)A_l + ds) = va[i];
      *(uint4*)((char*)B_l + ds) = vb[i];
    }
    __syncthreads();

    // --- MFMA: 4 s-steps per chunk ---
#pragma unroll
    for (int s = 0; s < 4; ++s) {
      const unsigned ks = (unsigned)(s * 64);
      short8 af = *(const short8*)((const char*)A_l + ((offA + ks) ^ swA));
      short8 b0 = *(const short8*)((const char*)B_l + ((offB0 + ks) ^ swB));
      short8 b1 = *(const short8*)((const char*)B_l + ((offB1 + ks) ^ swB));
      short8 b2 = *(const short8*)((const char*)B_l + ((offB2 + ks) ^ swB));
      short8 b3 = *(const short8*)((const char*)B_l + ((offB3 + ks) ^ swB));
      acc0 = __builtin_amdgcn_mfma_f32_16x16x32_bf16(af, b0, acc0, 0, 0, 0);
      acc1 = __builtin_amdgcn_mfma_f32_16x16x32_bf16(af, b1, acc1, 0, 0, 0);
      acc2 = __builtin_amdgcn_mfma_f32_16x16x32_bf16(af, b2, acc2, 0, 0, 0);
      acc3 = __builtin_amdgcn_mfma_f32_16x16x32_bf16(af, b3, acc3, 0, 0, 0);
    }
  }

  // --- epilogue: D col=lane&15, row=lg*4+r (HW-verified m89/m91) ---
  float* pb = partials +
      (((size_t)kp * 1024 + c * 256 + row0 + w * 16 + lg * 4) * 256) +
      col0 + lr;
#pragma unroll
  for (int r = 0; r < 4; ++r) {
    pb[r * 256 + 0]  = acc0[r];
    pb[r * 256 + 16] = acc1[r];
    pb[r * 256 + 32] = acc2[r];
    pb[r * 256 + 48] = acc3[r];
  }
}

// ---------- kernel 4: finalize ----------
__global__ __launch_bounds__(256) void gs_finalize(
    const float* __restrict__ partials, float* __restrict__ out) {
  int px = blockIdx.x * 256 + threadIdx.x;
  int row = px >> 8, col = px & 255;
  float s0 = 0.f, s1 = 0.f, s2 = 0.f, s3 = 0.f;
#pragma unroll
  for (int kp = 0; kp < KSPLIT; ++kp) {
    const float* base = partials + (((size_t)kp * 4) * 256 + row) * 256 + col;
    s0 += base[0 * 65536];
    s1 += base[1 * 65536];
    s2 += base[2 * 65536];
    s3 += base[3 * 65536];
  }
  float inv = 1.0f / fmaxf(s3, 1e-5f);
  out[0 * PIX + px] = fminf(fmaxf(s0 * inv, 0.0f), 1.0f);
  out[1 * PIX + px] = fminf(fmaxf(s1 * inv, 0.0f), 1.0f);
  out[2 * PIX + px] = fminf(fmaxf(s2 * inv, 0.0f), 1.0f);
}

extern "C" void kernel_launch(void* const* d_in, const int* in_sizes, int n_in,
                              void* d_out, int out_size, void* d_ws, size_t ws_size,
                              hipStream_t stream) {
  const float* means = (const float*)d_in[0];
  // d_in[1] = quats (unused by reference)
  const float* scales = (const float*)d_in[2];
  const float* opac = (const float*)d_in[3];
  const float* colors = (const float*)d_in[4];
  float* out = (float*)d_out;

  // ws layout (bytes):
  //   A_t      [4][256][2048] bf16 = 4 MB      @ 0
  //   B_t      [256][2048] bf16    = 1 MB      @ 4 MB
  //   partials [8][1024][256] f32  = 8 MB      @ 5 MB
  //   params   [2048] float4       = 32 KB     @ 13 MB
  //   colp     [2048] float4       = 32 KB     @ 13 MB + 32 KB
  char* ws = (char*)d_ws;
  unsigned short* A_t = (unsigned short*)ws;
  unsigned short* B_t = (unsigned short*)(ws + (4u << 20));
  float* partials = (float*)(ws + (5u << 20));
  float4* params = (float4*)(ws + (13u << 20));
  float4* colp = (float4*)(ws + (13u << 20) + 32768);

  gs_params<<<8, 256, 0, stream>>>(means, scales, opac, colors, params, colp);
  gs_tables<<<512, 256, 0, stream>>>(params, colp, A_t, B_t);
  gs_gemm<<<dim3(16, 4, KSPLIT), 256, 0, stream>>>(A_t, B_t, partials);
  gs_finalize<<<256, 256, 0, stream>>>(partials, out);
}

// Round 20
// 23.311 us; speedup vs baseline: 1.4432x; 1.4432x over previous
//
#include <hip/hip_runtime.h>

// GSplat renderer as a bf16 MFMA GEMM — R18 structure (best, 18.96us) with
// the partials round-trip replaced by global fp32 atomicAdd into a single
// [4][256][256] accum plane (1 MB, zeroed in-graph). R19's global-table split
// regressed (+14.7us): extra kernels + intermediate traffic cost more than
// the redundant exp2 they saved. Finalize now reads 1 MB instead of 8.

constexpr int PIX = 65536;
constexpr int KB = 256;      // gaussians per block (2 chunks of 128)
constexpr int KCH = 128;     // per staging chunk
constexpr int KSPLIT = 8;
constexpr int MT = 64;
constexpr int NT = 64;
constexpr float COORD_STEP = 2.0f / 255.0f;

typedef __attribute__((ext_vector_type(8))) short short8;
typedef __attribute__((ext_vector_type(4))) float f32x4;

__device__ __forceinline__ unsigned cvt_pk_bf16(float lo, float hi) {
  unsigned r;
  asm("v_cvt_pk_bf16_f32 %0, %1, %2" : "=v"(r) : "v"(lo), "v"(hi));
  return r;
}

__global__ __launch_bounds__(256) void gs_mfma(
    const float* __restrict__ means, const float* __restrict__ scales,
    const float* __restrict__ opac, const float* __restrict__ colors,
    float* __restrict__ accum) {
  __shared__ unsigned short A_l[MT * KCH];  // bf16 bits, swizzled (16 KB)
  __shared__ unsigned short B_l[NT * KCH];  // bf16 bits, swizzled (16 KB)
  __shared__ float pxL[KB], pyL[KB], kKL[KB], colL[KB];  // 4 KB

  const int t = threadIdx.x;
  const int mt = blockIdx.x;          // 0..15: c = mt>>2, rowband (mt&3)*64
  const int nt = blockIdx.y;          // 0..3
  const int kp = blockIdx.z;          // 0..7
  const int c = mt >> 2;
  const int row0 = (mt & 3) * MT;
  const int col0 = nt * NT;

  // --- params for BOTH chunks (1 gaussian per thread, once) ---
  {
    int n = kp * KB + t;
    float mx = means[3 * n], my = means[3 * n + 1], mz = means[3 * n + 2];
    float scl = fmaxf((scales[3 * n] + scales[3 * n + 1] + scales[3 * n + 2]) * (1.0f / 3.0f), 1e-4f);
    float op = opac[n];
    float rzs = 1.0f / (fabsf(mz) + 1.0f);
    float sigma = fminf(fmaxf(scl * rzs, 0.02f), 0.5f);
    float inv_s = 1.0f / sigma;
    pxL[t] = tanhf(mx * rzs);
    pyL[t] = tanhf(my * rzs);
    kKL[t] = -0.72134752044f * inv_s * inv_s;  // -0.5/ln2 * inv_s^2
    colL[t] = (c < 3) ? op * colors[3 * n + c] : op;
  }

  // MFMA lane mapping (constant across chunks)
  const int w = t >> 6;
  const int lr = t & 15;
  const int lg = (t >> 4) & 3;
  const int ra = w * 16 + lr;
  const unsigned offA = (unsigned)(ra * 256 + lg * 16);
  const unsigned swA = (unsigned)((ra & 7) << 4);
  const unsigned swB = (unsigned)((lr & 7) << 4);
  const unsigned offB0 = (unsigned)((0 * 16 + lr) * 256 + lg * 16);
  const unsigned offB1 = (unsigned)((1 * 16 + lr) * 256 + lg * 16);
  const unsigned offB2 = (unsigned)((2 * 16 + lr) * 256 + lg * 16);
  const unsigned offB3 = (unsigned)((3 * 16 + lr) * 256 + lg * 16);

  f32x4 acc0 = {0.f, 0.f, 0.f, 0.f};
  f32x4 acc1 = acc0, acc2 = acc0, acc3 = acc0;

  // staging thread mapping
  const int kq = (t & 31) << 2;       // 4 gaussians (local k)
  const int mq = (t >> 5) << 3;       // 8 rows/cols
  const int kbyte = (t & 31) << 3;

  for (int cc = 0; cc < 2; ++cc) {
    __syncthreads();   // params ready (cc=0) / prior MFMA reads done (cc=1)

    // --- stage A (ey*col) and Bt (ex), bf16, swizzled ---
    {
      const int kk = cc * KCH + kq;
      float py0 = pyL[kk + 0], py1 = pyL[kk + 1], py2 = pyL[kk + 2], py3 = pyL[kk + 3];
      float px0 = pxL[kk + 0], px1 = pxL[kk + 1], px2 = pxL[kk + 2], px3 = pxL[kk + 3];
      float K0 = kKL[kk + 0], K1 = kKL[kk + 1], K2 = kKL[kk + 2], K3 = kKL[kk + 3];
      float c0 = colL[kk + 0], c1 = colL[kk + 1], c2 = colL[kk + 2], c3 = colL[kk + 3];
#pragma unroll 4
      for (int j = 0; j < 8; ++j) {
        int m = mq + j;
        float cr = -1.0f + COORD_STEP * (float)(row0 + m);
        float d0 = cr - py0, d1 = cr - py1, d2 = cr - py2, d3 = cr - py3;
        float e0 = exp2f(K0 * d0 * d0) * c0;
        float e1 = exp2f(K1 * d1 * d1) * c1;
        float e2 = exp2f(K2 * d2 * d2) * c2;
        float e3 = exp2f(K3 * d3 * d3) * c3;
        uint2 pa;
        pa.x = cvt_pk_bf16(e0, e1);
        pa.y = cvt_pk_bf16(e2, e3);
        *(uint2*)((char*)A_l + ((m * 256 + kbyte) ^ ((m & 7) << 4))) = pa;
        float ccoord = -1.0f + COORD_STEP * (float)(col0 + m);
        float f0 = ccoord - px0, f1 = ccoord - px1, f2 = ccoord - px2, f3 = ccoord - px3;
        float g0 = exp2f(K0 * f0 * f0);
        float g1 = exp2f(K1 * f1 * f1);
        float g2 = exp2f(K2 * f2 * f2);
        float g3 = exp2f(K3 * f3 * f3);
        uint2 pb;
        pb.x = cvt_pk_bf16(g0, g1);
        pb.y = cvt_pk_bf16(g2, g3);
        *(uint2*)((char*)B_l + ((m * 256 + kbyte) ^ ((m & 7) << 4))) = pb;
      }
    }
    __syncthreads();

    // --- MFMA: 4 s-steps per chunk ---
#pragma unroll
    for (int s = 0; s < 4; ++s) {
      const unsigned ks = (unsigned)(s * 64);
      short8 af = *(const short8*)((const char*)A_l + ((offA + ks) ^ swA));
      short8 b0 = *(const short8*)((const char*)B_l + ((offB0 + ks) ^ swB));
      short8 b1 = *(const short8*)((const char*)B_l + ((offB1 + ks) ^ swB));
      short8 b2 = *(const short8*)((const char*)B_l + ((offB2 + ks) ^ swB));
      short8 b3 = *(const short8*)((const char*)B_l + ((offB3 + ks) ^ swB));
      acc0 = __builtin_amdgcn_mfma_f32_16x16x32_bf16(af, b0, acc0, 0, 0, 0);
      acc1 = __builtin_amdgcn_mfma_f32_16x16x32_bf16(af, b1, acc1, 0, 0, 0);
      acc2 = __builtin_amdgcn_mfma_f32_16x16x32_bf16(af, b2, acc2, 0, 0, 0);
      acc3 = __builtin_amdgcn_mfma_f32_16x16x32_bf16(af, b3, acc3, 0, 0, 0);
    }
  }

  // --- epilogue: atomic fp32 accumulate into [4][256][256] plane ---
  // D layout: col=lane&15, row=lg*4+r (HW-verified m89/m91).
  {
    float* ab = accum +
        ((size_t)(c * 256 + row0 + w * 16 + lg * 4) * 256) + col0 + lr;
#pragma unroll
    for (int r = 0; r < 4; ++r) {
      atomicAdd(&ab[r * 256 + 0],  acc0[r]);
      atomicAdd(&ab[r * 256 + 16], acc1[r]);
      atomicAdd(&ab[r * 256 + 32], acc2[r]);
      atomicAdd(&ab[r * 256 + 48], acc3[r]);
    }
  }
}

// grid = 256 blocks; thread = one pixel; 4 coalesced loads from accum (1 MB).
__global__ __launch_bounds__(256) void gs_finalize(
    const float* __restrict__ accum, float* __restrict__ out) {
  int px = blockIdx.x * 256 + threadIdx.x;
  float s0 = accum[0 * PIX + px];
  float s1 = accum[1 * PIX + px];
  float s2 = accum[2 * PIX + px];
  float s3 = accum[3 * PIX + px];
  float inv = 1.0f / fmaxf(s3, 1e-5f);
  out[0 * PIX + px] = fminf(fmaxf(s0 * inv, 0.0f), 1.0f);
  out[1 * PIX + px] = fminf(fmaxf(s1 * inv, 0.0f), 1.0f);
  out[2 * PIX + px] = fminf(fmaxf(s2 * inv, 0.0f), 1.0f);
}

extern "C" void kernel_launch(void* const* d_in, const int* in_sizes, int n_in,
                              void* d_out, int out_size, void* d_ws, size_t ws_size,
                              hipStream_t stream) {
  const float* means = (const float*)d_in[0];
  // d_in[1] = quats (unused by reference)
  const float* scales = (const float*)d_in[2];
  const float* opac = (const float*)d_in[3];
  const float* colors = (const float*)d_in[4];
  float* out = (float*)d_out;

  // ws: accum [4][256][256] fp32 = 1 MB (zeroed each call, in-graph)
  float* accum = (float*)d_ws;

  hipMemsetAsync(accum, 0, (size_t)4 * PIX * sizeof(float), stream);
  gs_mfma<<<dim3(16, 4, KSPLIT), 256, 0, stream>>>(
      means, scales, opac, colors, accum);
  gs_finalize<<<256, 256, 0, stream>>>(accum, out);
}

// Round 21
// 21.755 us; speedup vs baseline: 1.5464x; 1.0715x over previous
//
#include <hip/hip_runtime.h>

// GSplat renderer as a bf16 MFMA GEMM — R21: test TRUE multi-block/CU overlap.
// R18's grid (512 blocks) only ever gave 2 blocks/CU; the 36KB LDS headroom
// was never used. Now KSPLIT=16 -> grid (16,4,16)=1024 blocks = 4/CU, one
// 128-k chunk per block (work invariant). R20's atomics reverted (+4.35us).
// Partials [16][1024][256] fp32 = 16 MB; finalize reduces 16 parts.

constexpr int PIX = 65536;
constexpr int KCH = 128;     // gaussians per block
constexpr int KSPLIT = 16;
constexpr int MT = 64;
constexpr int NT = 64;
constexpr float COORD_STEP = 2.0f / 255.0f;

typedef __attribute__((ext_vector_type(8))) short short8;
typedef __attribute__((ext_vector_type(4))) float f32x4;

__device__ __forceinline__ unsigned cvt_pk_bf16(float lo, float hi) {
  unsigned r;
  asm("v_cvt_pk_bf16_f32 %0, %1, %2" : "=v"(r) : "v"(lo), "v"(hi));
  return r;
}

__global__ __launch_bounds__(256, 4) void gs_mfma(
    const float* __restrict__ means, const float* __restrict__ scales,
    const float* __restrict__ opac, const float* __restrict__ colors,
    float* __restrict__ partials) {
  __shared__ unsigned short A_l[MT * KCH];  // bf16 bits, swizzled (16 KB)
  __shared__ unsigned short B_l[NT * KCH];  // bf16 bits, swizzled (16 KB)
  __shared__ float pxL[KCH], pyL[KCH], kKL[KCH], colL[KCH];  // 2 KB

  const int t = threadIdx.x;
  const int mt = blockIdx.x;          // 0..15: c = mt>>2, rowband (mt&3)*64
  const int nt = blockIdx.y;          // 0..3
  const int kp = blockIdx.z;          // 0..15
  const int c = mt >> 2;
  const int row0 = (mt & 3) * MT;
  const int col0 = nt * NT;

  // --- params (threads 0..127, one gaussian each) ---
  if (t < KCH) {
    int n = kp * KCH + t;
    float mx = means[3 * n], my = means[3 * n + 1], mz = means[3 * n + 2];
    float scl = fmaxf((scales[3 * n] + scales[3 * n + 1] + scales[3 * n + 2]) * (1.0f / 3.0f), 1e-4f);
    float op = opac[n];
    float rzs = 1.0f / (fabsf(mz) + 1.0f);
    float sigma = fminf(fmaxf(scl * rzs, 0.02f), 0.5f);
    float inv_s = 1.0f / sigma;
    pxL[t] = tanhf(mx * rzs);
    pyL[t] = tanhf(my * rzs);
    kKL[t] = -0.72134752044f * inv_s * inv_s;  // -0.5/ln2 * inv_s^2
    colL[t] = (c < 3) ? op * colors[3 * n + c] : op;
  }
  __syncthreads();

  // --- stage A (ey*col) and Bt (ex), bf16, swizzled ---
  {
    const int kq = (t & 31) << 2;       // 4 gaussians (local k)
    const int mq = (t >> 5) << 3;       // 8 rows/cols
    const int kbyte = (t & 31) << 3;
    float py0 = pyL[kq + 0], py1 = pyL[kq + 1], py2 = pyL[kq + 2], py3 = pyL[kq + 3];
    float px0 = pxL[kq + 0], px1 = pxL[kq + 1], px2 = pxL[kq + 2], px3 = pxL[kq + 3];
    float K0 = kKL[kq + 0], K1 = kKL[kq + 1], K2 = kKL[kq + 2], K3 = kKL[kq + 3];
    float c0 = colL[kq + 0], c1 = colL[kq + 1], c2 = colL[kq + 2], c3 = colL[kq + 3];
#pragma unroll 4
    for (int j = 0; j < 8; ++j) {
      int m = mq + j;
      float cr = -1.0f + COORD_STEP * (float)(row0 + m);
      float d0 = cr - py0, d1 = cr - py1, d2 = cr - py2, d3 = cr - py3;
      float e0 = exp2f(K0 * d0 * d0) * c0;
      float e1 = exp2f(K1 * d1 * d1) * c1;
      float e2 = exp2f(K2 * d2 * d2) * c2;
      float e3 = exp2f(K3 * d3 * d3) * c3;
      uint2 pa;
      pa.x = cvt_pk_bf16(e0, e1);
      pa.y = cvt_pk_bf16(e2, e3);
      *(uint2*)((char*)A_l + ((m * 256 + kbyte) ^ ((m & 7) << 4))) = pa;
      float ccoord = -1.0f + COORD_STEP * (float)(col0 + m);
      float f0 = ccoord - px0, f1 = ccoord - px1, f2 = ccoord - px2, f3 = ccoord - px3;
      float g0 = exp2f(K0 * f0 * f0);
      float g1 = exp2f(K1 * f1 * f1);
      float g2 = exp2f(K2 * f2 * f2);
      float g3 = exp2f(K3 * f3 * f3);
      uint2 pb;
      pb.x = cvt_pk_bf16(g0, g1);
      pb.y = cvt_pk_bf16(g2, g3);
      *(uint2*)((char*)B_l + ((m * 256 + kbyte) ^ ((m & 7) << 4))) = pb;
    }
  }
  __syncthreads();

  // --- MFMA: 4 s-steps ---
  const int w = t >> 6;
  const int lr = t & 15;
  const int lg = (t >> 4) & 3;
  const int ra = w * 16 + lr;
  const unsigned offA = (unsigned)(ra * 256 + lg * 16);
  const unsigned swA = (unsigned)((ra & 7) << 4);
  const unsigned swB = (unsigned)((lr & 7) << 4);
  const unsigned offB0 = (unsigned)((0 * 16 + lr) * 256 + lg * 16);
  const unsigned offB1 = (unsigned)((1 * 16 + lr) * 256 + lg * 16);
  const unsigned offB2 = (unsigned)((2 * 16 + lr) * 256 + lg * 16);
  const unsigned offB3 = (unsigned)((3 * 16 + lr) * 256 + lg * 16);

  f32x4 acc0 = {0.f, 0.f, 0.f, 0.f};
  f32x4 acc1 = acc0, acc2 = acc0, acc3 = acc0;

#pragma unroll
  for (int s = 0; s < 4; ++s) {
    const unsigned ks = (unsigned)(s * 64);
    short8 af = *(const short8*)((const char*)A_l + ((offA + ks) ^ swA));
    short8 b0 = *(const short8*)((const char*)B_l + ((offB0 + ks) ^ swB));
    short8 b1 = *(const short8*)((const char*)B_l + ((offB1 + ks) ^ swB));
    short8 b2 = *(const short8*)((const char*)B_l + ((offB2 + ks) ^ swB));
    short8 b3 = *(const short8*)((const char*)B_l + ((offB3 + ks) ^ swB));
    acc0 = __builtin_amdgcn_mfma_f32_16x16x32_bf16(af, b0, acc0, 0, 0, 0);
    acc1 = __builtin_amdgcn_mfma_f32_16x16x32_bf16(af, b1, acc1, 0, 0, 0);
    acc2 = __builtin_amdgcn_mfma_f32_16x16x32_bf16(af, b2, acc2, 0, 0, 0);
    acc3 = __builtin_amdgcn_mfma_f32_16x16x32_bf16(af, b3, acc3, 0, 0, 0);
  }

  // --- epilogue: D col=lane&15, row=lg*4+r (HW-verified m89/m91) ---
  float* pb = partials +
      (((size_t)kp * 1024 + c * 256 + row0 + w * 16 + lg * 4) * 256) +
      col0 + lr;
#pragma unroll
  for (int r = 0; r < 4; ++r) {
    pb[r * 256 + 0]  = acc0[r];
    pb[r * 256 + 16] = acc1[r];
    pb[r * 256 + 32] = acc2[r];
    pb[r * 256 + 48] = acc3[r];
  }
}

// grid = 256 blocks; thread = one pixel.
__global__ __launch_bounds__(256) void gs_finalize(
    const float* __restrict__ partials, float* __restrict__ out) {
  int px = blockIdx.x * 256 + threadIdx.x;
  int row = px >> 8, col = px & 255;
  float s0 = 0.f, s1 = 0.f, s2 = 0.f, s3 = 0.f;
#pragma unroll 4
  for (int kp = 0; kp < KSPLIT; ++kp) {
    const float* base = partials + (((size_t)kp * 4) * 256 + row) * 256 + col;
    s0 += base[0 * 65536];
    s1 += base[1 * 65536];
    s2 += base[2 * 65536];
    s3 += base[3 * 65536];
  }
  float inv = 1.0f / fmaxf(s3, 1e-5f);
  out[0 * PIX + px] = fminf(fmaxf(s0 * inv, 0.0f), 1.0f);
  out[1 * PIX + px] = fminf(fmaxf(s1 * inv, 0.0f), 1.0f);
  out[2 * PIX + px] = fminf(fmaxf(s2 * inv, 0.0f), 1.0f);
}

extern "C" void kernel_launch(void* const* d_in, const int* in_sizes, int n_in,
                              void* d_out, int out_size, void* d_ws, size_t ws_size,
                              hipStream_t stream) {
  const float* means = (const float*)d_in[0];
  // d_in[1] = quats (unused by reference)
  const float* scales = (const float*)d_in[2];
  const float* opac = (const float*)d_in[3];
  const float* colors = (const float*)d_in[4];
  float* out = (float*)d_out;

  // ws: partials [KSPLIT][1024][256] fp32 = 16 MB
  float* partials = (float*)d_ws;

  gs_mfma<<<dim3(16, 4, KSPLIT), 256, 0, stream>>>(
      means, scales, opac, colors, partials);
  gs_finalize<<<256, 256, 0, stream>>>(partials, out);
}

// Round 22
// 16.821 us; speedup vs baseline: 2.0001x; 1.2933x over previous
//
#include <hip/hip_runtime.h>
#include <hip/hip_fp16.h>

// GSplat renderer as a bf16 MFMA GEMM — R22 = R18 (best, 18.96us) with fp16
// partials (8 MB -> 4 MB round-trip). R19/R20/R21 falsified global tables,
// atomics, and higher occupancy; totals track traffic+launches only.
// GEMM: M=1024 (4c x 256 rows), N=256, K=2048; KCH=128 x 2 chunks/block;
// grid (16,4,8) = 512 blocks = 2/CU; LDS 36 KB; XOR-swizzled LDS tiles.

constexpr int PIX = 65536;
constexpr int KB = 256;      // gaussians per block (2 chunks of 128)
constexpr int KCH = 128;     // per staging chunk
constexpr int KSPLIT = 8;
constexpr int MT = 64;
constexpr int NT = 64;
constexpr float COORD_STEP = 2.0f / 255.0f;

typedef __attribute__((ext_vector_type(8))) short short8;
typedef __attribute__((ext_vector_type(4))) float f32x4;

__device__ __forceinline__ unsigned cvt_pk_bf16(float lo, float hi) {
  unsigned r;
  asm("v_cvt_pk_bf16_f32 %0, %1, %2" : "=v"(r) : "v"(lo), "v"(hi));
  return r;
}

__global__ __launch_bounds__(256) void gs_mfma(
    const float* __restrict__ means, const float* __restrict__ scales,
    const float* __restrict__ opac, const float* __restrict__ colors,
    __half* __restrict__ partials) {
  __shared__ unsigned short A_l[MT * KCH];  // bf16 bits, swizzled (16 KB)
  __shared__ unsigned short B_l[NT * KCH];  // bf16 bits, swizzled (16 KB)
  __shared__ float pxL[KB], pyL[KB], kKL[KB], colL[KB];  // 4 KB

  const int t = threadIdx.x;
  const int mt = blockIdx.x;          // 0..15: c = mt>>2, rowband (mt&3)*64
  const int nt = blockIdx.y;          // 0..3
  const int kp = blockIdx.z;          // 0..7
  const int c = mt >> 2;
  const int row0 = (mt & 3) * MT;
  const int col0 = nt * NT;

  // --- params for BOTH chunks (1 gaussian per thread, once) ---
  {
    int n = kp * KB + t;
    float mx = means[3 * n], my = means[3 * n + 1], mz = means[3 * n + 2];
    float scl = fmaxf((scales[3 * n] + scales[3 * n + 1] + scales[3 * n + 2]) * (1.0f / 3.0f), 1e-4f);
    float op = opac[n];
    float rzs = 1.0f / (fabsf(mz) + 1.0f);
    float sigma = fminf(fmaxf(scl * rzs, 0.02f), 0.5f);
    float inv_s = 1.0f / sigma;
    pxL[t] = tanhf(mx * rzs);
    pyL[t] = tanhf(my * rzs);
    kKL[t] = -0.72134752044f * inv_s * inv_s;  // -0.5/ln2 * inv_s^2
    colL[t] = (c < 3) ? op * colors[3 * n + c] : op;
  }

  // MFMA lane mapping (constant across chunks)
  const int w = t >> 6;
  const int lr = t & 15;
  const int lg = (t >> 4) & 3;
  const int ra = w * 16 + lr;
  const unsigned offA = (unsigned)(ra * 256 + lg * 16);
  const unsigned swA = (unsigned)((ra & 7) << 4);
  const unsigned swB = (unsigned)((lr & 7) << 4);
  const unsigned offB0 = (unsigned)((0 * 16 + lr) * 256 + lg * 16);
  const unsigned offB1 = (unsigned)((1 * 16 + lr) * 256 + lg * 16);
  const unsigned offB2 = (unsigned)((2 * 16 + lr) * 256 + lg * 16);
  const unsigned offB3 = (unsigned)((3 * 16 + lr) * 256 + lg * 16);

  f32x4 acc0 = {0.f, 0.f, 0.f, 0.f};
  f32x4 acc1 = acc0, acc2 = acc0, acc3 = acc0;

  // staging thread mapping
  const int kq = (t & 31) << 2;       // 4 gaussians (local k)
  const int mq = (t >> 5) << 3;       // 8 rows/cols
  const int kbyte = (t & 31) << 3;

  for (int cc = 0; cc < 2; ++cc) {
    __syncthreads();   // params ready (cc=0) / prior MFMA reads done (cc=1)

    // --- stage A (ey*col) and Bt (ex), bf16, swizzled ---
    {
      const int kk = cc * KCH + kq;
      float py0 = pyL[kk + 0], py1 = pyL[kk + 1], py2 = pyL[kk + 2], py3 = pyL[kk + 3];
      float px0 = pxL[kk + 0], px1 = pxL[kk + 1], px2 = pxL[kk + 2], px3 = pxL[kk + 3];
      float K0 = kKL[kk + 0], K1 = kKL[kk + 1], K2 = kKL[kk + 2], K3 = kKL[kk + 3];
      float c0 = colL[kk + 0], c1 = colL[kk + 1], c2 = colL[kk + 2], c3 = colL[kk + 3];
#pragma unroll 4
      for (int j = 0; j < 8; ++j) {
        int m = mq + j;
        float cr = -1.0f + COORD_STEP * (float)(row0 + m);
        float d0 = cr - py0, d1 = cr - py1, d2 = cr - py2, d3 = cr - py3;
        float e0 = exp2f(K0 * d0 * d0) * c0;
        float e1 = exp2f(K1 * d1 * d1) * c1;
        float e2 = exp2f(K2 * d2 * d2) * c2;
        float e3 = exp2f(K3 * d3 * d3) * c3;
        uint2 pa;
        pa.x = cvt_pk_bf16(e0, e1);
        pa.y = cvt_pk_bf16(e2, e3);
        *(uint2*)((char*)A_l + ((m * 256 + kbyte) ^ ((m & 7) << 4))) = pa;
        float ccoord = -1.0f + COORD_STEP * (float)(col0 + m);
        float f0 = ccoord - px0, f1 = ccoord - px1, f2 = ccoord - px2, f3 = ccoord - px3;
        float g0 = exp2f(K0 * f0 * f0);
        float g1 = exp2f(K1 * f1 * f1);
        float g2 = exp2f(K2 * f2 * f2);
        float g3 = exp2f(K3 * f3 * f3);
        uint2 pb;
        pb.x = cvt_pk_bf16(g0, g1);
        pb.y = cvt_pk_bf16(g2, g3);
        *(uint2*)((char*)B_l + ((m * 256 + kbyte) ^ ((m & 7) << 4))) = pb;
      }
    }
    __syncthreads();

    // --- MFMA: 4 s-steps per chunk ---
#pragma unroll
    for (int s = 0; s < 4; ++s) {
      const unsigned ks = (unsigned)(s * 64);
      short8 af = *(const short8*)((const char*)A_l + ((offA + ks) ^ swA));
      short8 b0 = *(const short8*)((const char*)B_l + ((offB0 + ks) ^ swB));
      short8 b1 = *(const short8*)((const char*)B_l + ((offB1 + ks) ^ swB));
      short8 b2 = *(const short8*)((const char*)B_l + ((offB2 + ks) ^ swB));
      short8 b3 = *(const short8*)((const char*)B_l + ((offB3 + ks) ^ swB));
      acc0 = __builtin_amdgcn_mfma_f32_16x16x32_bf16(af, b0, acc0, 0, 0, 0);
      acc1 = __builtin_amdgcn_mfma_f32_16x16x32_bf16(af, b1, acc1, 0, 0, 0);
      acc2 = __builtin_amdgcn_mfma_f32_16x16x32_bf16(af, b2, acc2, 0, 0, 0);
      acc3 = __builtin_amdgcn_mfma_f32_16x16x32_bf16(af, b3, acc3, 0, 0, 0);
    }
  }

  // --- epilogue: fp16 partials; D col=lane&15, row=lg*4+r (m89/m91) ---
  {
    __half* pb = partials +
        (((size_t)kp * 1024 + c * 256 + row0 + w * 16 + lg * 4) * 256) +
        col0 + lr;
#pragma unroll
    for (int r = 0; r < 4; ++r) {
      pb[r * 256 + 0]  = __float2half(acc0[r]);
      pb[r * 256 + 16] = __float2half(acc1[r]);
      pb[r * 256 + 32] = __float2half(acc2[r]);
      pb[r * 256 + 48] = __float2half(acc3[r]);
    }
  }
}

// grid = 256 blocks; thread = one pixel.
__global__ __launch_bounds__(256) void gs_finalize(
    const __half* __restrict__ partials, float* __restrict__ out) {
  int px = blockIdx.x * 256 + threadIdx.x;
  int row = px >> 8, col = px & 255;
  float s0 = 0.f, s1 = 0.f, s2 = 0.f, s3 = 0.f;
#pragma unroll
  for (int kp = 0; kp < KSPLIT; ++kp) {
    const __half* base = partials + (((size_t)kp * 4) * 256 + row) * 256 + col;
    s0 += __half2float(base[0 * 65536]);
    s1 += __half2float(base[1 * 65536]);
    s2 += __half2float(base[2 * 65536]);
    s3 += __half2float(base[3 * 65536]);
  }
  float inv = 1.0f / fmaxf(s3, 1e-5f);
  out[0 * PIX + px] = fminf(fmaxf(s0 * inv, 0.0f), 1.0f);
  out[1 * PIX + px] = fminf(fmaxf(s1 * inv, 0.0f), 1.0f);
  out[2 * PIX + px] = fminf(fmaxf(s2 * inv, 0.0f), 1.0f);
}

extern "C" void kernel_launch(void* const* d_in, const int* in_sizes, int n_in,
                              void* d_out, int out_size, void* d_ws, size_t ws_size,
                              hipStream_t stream) {
  const float* means = (const float*)d_in[0];
  // d_in[1] = quats (unused by reference)
  const float* scales = (const float*)d_in[2];
  const float* opac = (const float*)d_in[3];
  const float* colors = (const float*)d_in[4];
  float* out = (float*)d_out;

  // ws: partials [KSPLIT][1024][256] fp16 = 4 MB
  __half* partials = (__half*)d_ws;

  gs_mfma<<<dim3(16, 4, KSPLIT), 256, 0, stream>>>(
      means, scales, opac, colors, partials);
  gs_finalize<<<256, 256, 0, stream>>>(partials, out);
}